// Round 13
// baseline (182.335 us; speedup 1.0000x reference)
//
#include <hip/hip_runtime.h>
#include <hip/hip_bf16.h>
#include <stdint.h>

typedef __hip_bfloat16 bf16_t;
typedef __attribute__((ext_vector_type(8))) __bf16 bf16x8;
typedef __attribute__((ext_vector_type(16))) float f32x16;
typedef __attribute__((ext_vector_type(8))) unsigned short ushort8;
typedef __attribute__((ext_vector_type(2))) unsigned long long u64x2;

#define BM 256
#define BN 256
#define BK 64
#define THREADS 512
#define OPBYTES 32768   // one operand per buf: 256 rows x 128 B
#define BUFBYTES 65536  // A + B
#define LDS_TOTAL 131072

// ---------------- fused quantize: q = rint(v*100)/100, cast to bf16 ----------------
__global__ __launch_bounds__(256) void quant2_bf16_kernel(
    const float* __restrict__ x, const float* __restrict__ w,
    bf16_t* __restrict__ q, long axn8, long totn8) {
  long idx = (long)blockIdx.x * blockDim.x + threadIdx.x;
  long stride = (long)gridDim.x * blockDim.x;
  for (long i = idx; i < totn8; i += stride) {
    const float* src = (i < axn8) ? (x + i * 8) : (w + (i - axn8) * 8);
    const float4* p = reinterpret_cast<const float4*>(src);
    float4 v0 = p[0];
    float4 v1 = p[1];
    float vv[8] = {v0.x, v0.y, v0.z, v0.w, v1.x, v1.y, v1.z, v1.w};
    ushort8 r;
#pragma unroll
    for (int j = 0; j < 8; ++j) {
      float qq = rintf(vv[j] * 100.0f) / 100.0f;  // half-to-even, matches jnp.round
      __hip_bfloat16 h = __float2bfloat16(qq);
      r[j] = __builtin_bit_cast(unsigned short, h);
    }
    u64x2 u = __builtin_bit_cast(u64x2, r);
    unsigned long long* dst = reinterpret_cast<unsigned long long*>(q + i * 8);
    __hip_atomic_store(dst + 0, u[0], __ATOMIC_RELAXED, __HIP_MEMORY_SCOPE_AGENT);
    __hip_atomic_store(dst + 1, u[1], __ATOMIC_RELAXED, __HIP_MEMORY_SCOPE_AGENT);
  }
}

// ---------------- fallback ----------------
__global__ void naive_kernel(const float* __restrict__ x, const float* __restrict__ W,
                             const float* __restrict__ b, float* __restrict__ out,
                             int M, int N, int K) {
  int o = blockIdx.x * blockDim.x + threadIdx.x;
  int m = blockIdx.y;
  if (o >= N || m >= M) return;
  float s = 0.f;
  for (int k = 0; k < K; ++k) {
    float qx = rintf(x[(size_t)m * K + k] * 100.f) / 100.f;
    float qw = rintf(W[(size_t)o * K + k] * 100.f) / 100.f;
    s += qx * qw;
  }
  float v = s + b[o];
  __hip_atomic_store(out + (size_t)m * N + o, v, __ATOMIC_RELAXED,
                     __HIP_MEMORY_SCOPE_AGENT);
}

__device__ __forceinline__ void gload_lds16(const bf16_t* g, const char* l) {
  __builtin_amdgcn_global_load_lds(
      (const __attribute__((address_space(1))) unsigned int*)g,
      (__attribute__((address_space(3))) unsigned int*)l, 16, 0, 0);
}

#define BARRIER()                               \
  do {                                          \
    asm volatile("" ::: "memory");              \
    __builtin_amdgcn_s_barrier();               \
    asm volatile("" ::: "memory");              \
  } while (0)
#define VM6() asm volatile("s_waitcnt vmcnt(6)" ::: "memory")
#define VM0() asm volatile("s_waitcnt vmcnt(0)" ::: "memory")

// ---------------- bf16 GEMM, B^T input: C[m][n] = sum_k A[m][k]*B[n][k] + bias[n]
// ROUND 13 = r12 schedule + 32x32x16 MFMA (m119: 2495 TF vs 2075 for 16x16 ->
// MFMA floor/iter 4966 -> ~4133 cyc; half the MFMA instructions). Six schedule
// variants (r6-r12) all pinned at 46-49% MfmaUtil with per-iter cycles = MFMA
// floor + LDS-read time (serial sum) -> the movable term is the MFMA floor.
//
// Per wave: output 128x64 = 4 m-tiles (32 rows) x 2 n-tiles (32 cols),
// acc = f32x16 acc32[4][2] (128 regs, same as before). Per K-tile (BK=64,
// 4 k-slices of 16): 32 MFMA(32x32x16) in 4 quadrant phases of 8.
// A-operand layout (analogy to verified 16x16x32: row = lane mod M,
// k-group = lane div M): row = lane&31, k = (lane>>5)*8 + j. Read = 16B at
// byte row*128 + slot*16, slot = (lane>>5) | 2ks; swizzled slot ^= (row&7);
// ks-step is XOR (ks<<5) since (lg5 | 2ks) has disjoint bits. B identical on
// its [col][k] panel. C/D layout (HW-verified m74/m101): col = lane&31,
// row = (reg&3) + 8*(reg>>2) + 4*(lane>>5).
//
// Staging + vmcnt ledger IDENTICAL to r12 (one 2-load STAGE per phase):
//   ph1: b1.A1(t1)  ph2: b0.B0(t2)  ph3: b0.B1(t2)  ph4: b0.A0(t2)+VM6
//   ph5: b0.A1(t2)  ph6: b1.B0(t3)  ph7: b1.B1(t3)  ph8: b1.A0(t3)+VM6
// WAR/RAW proofs as in r12 (>=1 barrier between region's last read and its
// overwrite; VM6 retires exactly one tile, 4-7 phases old). Prologue 14 loads
// + VM6; LAST iteration peeled (only ph1's stage; VM0 at ph4).
// LDS swizzle: 128B rows, stored slot = slot ^ (row&7). global_load_lds dest
// linear; swizzle on the global SOURCE (rule #21).
__global__ __launch_bounds__(THREADS, 2) void gemm_bt_bf16(
    const bf16_t* __restrict__ A,   // [M][K]
    const bf16_t* __restrict__ B,   // [N][K]
    const float* __restrict__ bias, // [N]
    float* __restrict__ C,          // [M][N]
    int M, int N, int K) {
  extern __shared__ char lds[];

  const int tid = threadIdx.x;
  const int lane = tid & 63;
  const int wave = tid >> 6;  // 0..7
  const int wm = wave >> 2;   // 0..1 -> output rows wm*128..+128
  const int wn = wave & 3;    // 0..3 -> output cols wn*64..+64
  const int lr5 = lane & 31;
  const int lg5 = lane >> 5;

  // XCD-aware bijective swizzle (nwg % 8 == 0 guaranteed by tiled_ok)
  int nbn = N / BN;
  int nwg = gridDim.x;
  int bid = blockIdx.x;
  int swz = bid;
  if ((nwg & 7) == 0) {
    int cpx = nwg >> 3;
    swz = (bid & 7) * cpx + (bid >> 3);
  }
  const int brow = (swz / nbn) * BM;
  const int bcol = (swz % nbn) * BN;

  // ds_read byte offsets at ks=0 (ks-step = XOR (ks<<5))
  int aoffs[4], boffs[2];
#pragma unroll
  for (int mt = 0; mt < 4; ++mt) {
    int r = wm * 128 + mt * 32 + lr5;
    aoffs[mt] = r * 128 + ((lg5 ^ (r & 7)) << 4);
  }
#pragma unroll
  for (int nt = 0; nt < 2; ++nt) {
    int r = wn * 64 + nt * 32 + lr5;
    boffs[nt] = OPBYTES + r * 128 + ((lg5 ^ (r & 7)) << 4);
  }

  f32x16 acc32[4][2];
#pragma unroll
  for (int mt = 0; mt < 4; ++mt)
#pragma unroll
    for (int nt = 0; nt < 2; ++nt)
#pragma unroll
      for (int j = 0; j < 16; ++j) acc32[mt][nt][j] = 0.f;

  const int nt_tiles = K / BK;

  auto STAGE_A = [&](int h, int kt, int q) {
#pragma unroll
    for (int i = 0; i < 2; ++i) {
      int row = h * 128 + i * 64 + (tid >> 3);
      int L = q * BUFBYTES + row * 128 + ((tid & 7) << 4);
      int slot = (tid & 7) ^ (row & 7);
      gload_lds16(A + (size_t)(brow + row) * K + (size_t)kt * 64 + slot * 8,
                  lds + L);
    }
  };
  auto STAGE_B = [&](int h, int kt, int q) {
#pragma unroll
    for (int i = 0; i < 2; ++i) {
      int row = h * 128 + i * 64 + (tid >> 3);
      int L = q * BUFBYTES + OPBYTES + row * 128 + ((tid & 7) << 4);
      int slot = (tid & 7) ^ (row & 7);
      gload_lds16(B + (size_t)(bcol + row) * K + (size_t)kt * 64 + slot * 8,
                  lds + L);
    }
  };

  bf16x8 aq[8], blo[4], bhi[4];  // aq[(mt&1)*4+ks]; b*[ks]
  auto READ_A = [&](int q, int mh) {
#pragma unroll
    for (int m2 = 0; m2 < 2; ++m2) {
      int base = q * BUFBYTES + aoffs[mh * 2 + m2];
#pragma unroll
      for (int ks = 0; ks < 4; ++ks)
        aq[m2 * 4 + ks] = *reinterpret_cast<const bf16x8*>(lds + (base ^ (ks << 5)));
    }
  };
  auto READ_B = [&](int q, int nh, bf16x8* dst) {
    int base = q * BUFBYTES + boffs[nh];
#pragma unroll
    for (int ks = 0; ks < 4; ++ks)
      dst[ks] = *reinterpret_cast<const bf16x8*>(lds + (base ^ (ks << 5)));
  };
  // ks-outer: the two acc chains (m2=0,1) alternate -> dependent same-acc
  // MFMAs are 2 apart; 2 waves/SIMD fill the rest.
  auto MMA = [&](int mh, int nh, const bf16x8* bb) {
    __builtin_amdgcn_s_setprio(1);
#pragma unroll
    for (int ks = 0; ks < 4; ++ks)
#pragma unroll
      for (int m2 = 0; m2 < 2; ++m2)
        acc32[mh * 2 + m2][nh] = __builtin_amdgcn_mfma_f32_32x32x16_bf16(
            aq[m2 * 4 + ks], bb[ks], acc32[mh * 2 + m2][nh], 0, 0, 0);
    __builtin_amdgcn_s_setprio(0);
  };

  // Prologue: t0 full + t1 {B0,B1,A0} (14 loads); VM6 retires t0's 8,
  // keeps t1's 6 in flight.
  STAGE_B(0, 0, 0); STAGE_B(1, 0, 0); STAGE_A(0, 0, 0); STAGE_A(1, 0, 0);
  STAGE_B(0, 1, 1); STAGE_B(1, 1, 1); STAGE_A(0, 1, 1);
  VM6();
  BARRIER();

  const int np = nt_tiles >> 1;
  for (int p = 0; p < np - 1; ++p) {
    const int t1 = 2 * p + 1, t2 = 2 * p + 2, t3 = 2 * p + 3;
    // ph1: buf0 (m-lo,n-lo); stage b1.A1(t1)
    READ_B(0, 0, blo); READ_A(0, 0);
    STAGE_A(1, t1, 1);
    MMA(0, 0, blo);
    BARRIER();
    // ph2: (m-lo,n-hi); stage b0.B0(t2)
    READ_B(0, 1, bhi);
    STAGE_B(0, t2, 0);
    MMA(0, 1, bhi);
    BARRIER();
    // ph3: (m-hi,n-hi); stage b0.B1(t2)
    READ_A(0, 1);
    STAGE_B(1, t2, 0);
    MMA(1, 1, bhi);
    BARRIER();
    // ph4: (m-hi,n-lo); stage b0.A0(t2); VM6 retires tile t1
    STAGE_A(0, t2, 0);
    MMA(1, 0, blo);
    VM6();
    BARRIER();
    // ph5: buf1 (m-lo,n-lo); stage b0.A1(t2)
    READ_B(1, 0, blo); READ_A(1, 0);
    STAGE_A(1, t2, 0);
    MMA(0, 0, blo);
    BARRIER();
    // ph6: stage b1.B0(t3)
    READ_B(1, 1, bhi);
    STAGE_B(0, t3, 1);
    MMA(0, 1, bhi);
    BARRIER();
    // ph7: stage b1.B1(t3)
    READ_A(1, 1);
    STAGE_B(1, t3, 1);
    MMA(1, 1, bhi);
    BARRIER();
    // ph8: stage b1.A0(t3); VM6 retires tile t2
    STAGE_A(0, t3, 1);
    MMA(1, 0, blo);
    VM6();
    BARRIER();
  }

  // Peeled final iteration: only ph1's stage (b1.A1(nt-1)); VM0 at ph4.
  {
    const int t1f = nt_tiles - 1;
    READ_B(0, 0, blo); READ_A(0, 0);
    STAGE_A(1, t1f, 1);
    MMA(0, 0, blo);
    BARRIER();
    READ_B(0, 1, bhi);
    MMA(0, 1, bhi);
    BARRIER();
    READ_A(0, 1);
    MMA(1, 1, bhi);
    BARRIER();
    MMA(1, 0, blo);
    VM0();
    BARRIER();
    READ_B(1, 0, blo); READ_A(1, 0);
    MMA(0, 0, blo);
    BARRIER();
    READ_B(1, 1, bhi);
    MMA(0, 1, bhi);
    BARRIER();
    READ_A(1, 1);
    MMA(1, 1, bhi);
    BARRIER();
    MMA(1, 0, blo);
  }

  // Epilogue: 32x32 C/D layout col=lane&31, row=(reg&3)+8*(reg>>2)+4*(lane>>5)
  // [m74/m101]. Agent-scope stores (replay-safe visibility past per-XCD L2).
#pragma unroll
  for (int nt = 0; nt < 2; ++nt) {
    const int gcol = bcol + wn * 64 + nt * 32 + lr5;
    const float bv = bias[gcol];
#pragma unroll
    for (int mt = 0; mt < 4; ++mt) {
      const int rbase = brow + wm * 128 + mt * 32 + 4 * lg5;
#pragma unroll
      for (int r = 0; r < 16; ++r) {
        const int grow = rbase + (r & 3) + 8 * (r >> 2);
        float v = acc32[mt][nt][r] + bv;
        __hip_atomic_store(C + (size_t)grow * N + gcol, v, __ATOMIC_RELAXED,
                           __HIP_MEMORY_SCOPE_AGENT);
      }
    }
  }
}

extern "C" void kernel_launch(void* const* d_in, const int* in_sizes, int n_in,
                              void* d_out, int out_size, void* d_ws, size_t ws_size,
                              hipStream_t stream) {
  const float* x = (const float*)d_in[0];
  const float* W = (const float*)d_in[1];
  const float* b = (const float*)d_in[2];
  float* out = (float*)d_out;

  const int N = in_sizes[2];       // D_OUT
  const int K = in_sizes[1] / N;   // D_IN
  const int M = in_sizes[0] / K;   // B rows

  const size_t needA = (size_t)M * K * sizeof(bf16_t);
  const size_t needB = (size_t)N * K * sizeof(bf16_t);
  const bool tiled_ok = (M % BM == 0) && (N % BN == 0) && (K % (2 * BK) == 0) &&
                        (K / BK >= 2) && (ws_size >= needA + needB);
  if (!tiled_ok) {
    dim3 g((unsigned)((N + 255) / 256), (unsigned)M);
    naive_kernel<<<g, 256, 0, stream>>>(x, W, b, out, M, N, K);
    return;
  }

  bf16_t* qA = (bf16_t*)d_ws;
  bf16_t* qB = qA + (size_t)M * K;
  const long axn8 = (long)M * K / 8;
  const long totn8 = axn8 + (long)N * K / 8;
  quant2_bf16_kernel<<<2048, 256, 0, stream>>>(x, W, qA, axn8, totn8);

  (void)hipFuncSetAttribute((const void*)gemm_bt_bf16,
                            hipFuncAttributeMaxDynamicSharedMemorySize, LDS_TOTAL);

  const int nwg = (M / BM) * (N / BN);
  gemm_bt_bf16<<<nwg, THREADS, LDS_TOTAL, stream>>>(qA, qB, b, out, M, N, K);
}

// Round 14
// 166.410 us; speedup vs baseline: 1.0957x; 1.0957x over previous
//
#include <hip/hip_runtime.h>
#include <hip/hip_bf16.h>
#include <stdint.h>

typedef __hip_bfloat16 bf16_t;
typedef __attribute__((ext_vector_type(8))) __bf16 bf16x8;
typedef __attribute__((ext_vector_type(4))) float f32x4;
typedef __attribute__((ext_vector_type(8))) unsigned short ushort8;
typedef __attribute__((ext_vector_type(2))) unsigned long long u64x2;

#define BM 256
#define BN 256
#define BK 64
#define THREADS 512
#define OPBYTES 32768   // one operand per buf: 256 rows x 128 B
#define BUFBYTES 65536  // A + B
#define LDS_TOTAL 131072

// ---------------- fused quantize: q = rint(v*100)/100, cast to bf16 ----------------
__global__ __launch_bounds__(256) void quant2_bf16_kernel(
    const float* __restrict__ x, const float* __restrict__ w,
    bf16_t* __restrict__ q, long axn8, long totn8) {
  long idx = (long)blockIdx.x * blockDim.x + threadIdx.x;
  long stride = (long)gridDim.x * blockDim.x;
  for (long i = idx; i < totn8; i += stride) {
    const float* src = (i < axn8) ? (x + i * 8) : (w + (i - axn8) * 8);
    const float4* p = reinterpret_cast<const float4*>(src);
    float4 v0 = p[0];
    float4 v1 = p[1];
    float vv[8] = {v0.x, v0.y, v0.z, v0.w, v1.x, v1.y, v1.z, v1.w};
    ushort8 r;
#pragma unroll
    for (int j = 0; j < 8; ++j) {
      float qq = rintf(vv[j] * 100.0f) / 100.0f;  // half-to-even, matches jnp.round
      __hip_bfloat16 h = __float2bfloat16(qq);
      r[j] = __builtin_bit_cast(unsigned short, h);
    }
    u64x2 u = __builtin_bit_cast(u64x2, r);
    unsigned long long* dst = reinterpret_cast<unsigned long long*>(q + i * 8);
    __hip_atomic_store(dst + 0, u[0], __ATOMIC_RELAXED, __HIP_MEMORY_SCOPE_AGENT);
    __hip_atomic_store(dst + 1, u[1], __ATOMIC_RELAXED, __HIP_MEMORY_SCOPE_AGENT);
  }
}

// ---------------- fallback ----------------
__global__ void naive_kernel(const float* __restrict__ x, const float* __restrict__ W,
                             const float* __restrict__ b, float* __restrict__ out,
                             int M, int N, int K) {
  int o = blockIdx.x * blockDim.x + threadIdx.x;
  int m = blockIdx.y;
  if (o >= N || m >= M) return;
  float s = 0.f;
  for (int k = 0; k < K; ++k) {
    float qx = rintf(x[(size_t)m * K + k] * 100.f) / 100.f;
    float qw = rintf(W[(size_t)o * K + k] * 100.f) / 100.f;
    s += qx * qw;
  }
  float v = s + b[o];
  __hip_atomic_store(out + (size_t)m * N + o, v, __ATOMIC_RELAXED,
                     __HIP_MEMORY_SCOPE_AGENT);
}

__device__ __forceinline__ void gload_lds16(const bf16_t* g, const char* l) {
  __builtin_amdgcn_global_load_lds(
      (const __attribute__((address_space(1))) unsigned int*)g,
      (__attribute__((address_space(3))) unsigned int*)l, 16, 0, 0);
}

#define BARRIER()                               \
  do {                                          \
    asm volatile("" ::: "memory");              \
    __builtin_amdgcn_s_barrier();               \
    asm volatile("" ::: "memory");              \
  } while (0)
#define LGKM0() asm volatile("s_waitcnt lgkmcnt(0)" ::: "memory")
#define LGKM8() asm volatile("s_waitcnt lgkmcnt(8)" ::: "memory")
#define VM6() asm volatile("s_waitcnt vmcnt(6)" ::: "memory")
#define VM0() asm volatile("s_waitcnt vmcnt(0)" ::: "memory")

// ---------------- bf16 GEMM, B^T input: C[m][n] = sum_k A[m][k]*B[n][k] + bias[n]
// ROUND 14 = r12 ledger + the m201 template's TWO-BARRIER phase discipline:
//   phase = { ds_reads; stage (2 gloads); [lgkmcnt(8) if 12 reads];
//             s_barrier; lgkmcnt(0); setprio(1); 16 MFMA; setprio(0); s_barrier }
// Mechanism (m201/m218): reads issue BEFORE BAR1 -> LDS return latency drains
// under barrier-arrival skew; lgkm0 AFTER the barrier -> MFMA burst starts
// immediately; the wave reaches BAR2 after MFMA *issue* (acc not consumed
// until 2 phases later) -> next phase's read burst overlaps the MFMA drain.
// r6-r12 (one barrier, reads+MFMA in one window) pinned at 46-49% MfmaUtil =
// serial sum; the template measures ~6600 cyc/iter vs my 9100 on identical
// geometry. 32x32 MFMA (r13) reverted: 128B-row layout makes 32-lane reads
// inherently 4-way bank-conflicted (slot-only banking; measured 1.26e7).
//
// Stage schedule + vmcnt ledger (r12, proven): one 2-load STAGE per phase:
//   ph1: b1.A1(t1)  ph2: b0.B0(t2)  ph3: b0.B1(t2)  ph4: b0.A0(t2)+VM6
//   ph5: b0.A1(t2)  ph6: b1.B0(t3)  ph7: b1.B1(t3)  ph8: b1.A0(t3)+VM6
// VM6 = template's N = LOADS_PER_HALFTILE(2) x half-tiles-in-flight(3).
// ph4 VM6: 14 outstanding -> retires 8 = exactly tile t1 (4-7 phases old);
// ph8 VM6 retires exactly tile t2. Prologue 14 loads + VM6. WAR: each region
// staged >=1 barrier after its last read (now >=2 barriers - stronger).
// LAST iteration PEELED: only ph1's stage; VM0 at ph4.
// Reads: ph1 blo+Alo(12, lgkm8); ph2 bhi(4); ph3 Ahi(8); ph4 none; ph5-8 mirror.
// LDS swizzle: 128B rows, stored slot = slot ^ (row&7) (0 conflicts r2-r12).
// global_load_lds dest linear; swizzle on the global SOURCE (rule #21).
__global__ __launch_bounds__(THREADS, 2) void gemm_bt_bf16(
    const bf16_t* __restrict__ A,   // [M][K]
    const bf16_t* __restrict__ B,   // [N][K]
    const float* __restrict__ bias, // [N]
    float* __restrict__ C,          // [M][N]
    int M, int N, int K) {
  extern __shared__ char lds[];

  const int tid = threadIdx.x;
  const int lane = tid & 63;
  const int wave = tid >> 6;  // 0..7
  const int wm = wave >> 2;   // 0..1 -> output rows wm*128..+128
  const int wn = wave & 3;    // 0..3 -> output cols wn*64..+64
  const int lr = lane & 15;
  const int lg = lane >> 4;

  // XCD-aware bijective swizzle (nwg % 8 == 0 guaranteed by tiled_ok)
  int nbn = N / BN;
  int nwg = gridDim.x;
  int bid = blockIdx.x;
  int swz = bid;
  if ((nwg & 7) == 0) {
    int cpx = nwg >> 3;
    swz = (bid & 7) * cpx + (bid >> 3);
  }
  const int brow = (swz / nbn) * BM;
  const int bcol = (swz % nbn) * BN;

  // ds_read byte offsets within an operand region (kk=0; kk=1 is ^64)
  int aoffs[8], boffs[4];
#pragma unroll
  for (int m = 0; m < 8; ++m) {
    int r = wm * 128 + m * 16 + lr;
    aoffs[m] = r * 128 + (((lg) ^ (r & 7)) << 4);
  }
#pragma unroll
  for (int n = 0; n < 4; ++n) {
    int r = wn * 64 + n * 16 + lr;
    boffs[n] = r * 128 + (((lg) ^ (r & 7)) << 4);
  }

  f32x4 acc[8][4];
#pragma unroll
  for (int m = 0; m < 8; ++m)
#pragma unroll
    for (int n = 0; n < 4; ++n) acc[m][n] = (f32x4){0.f, 0.f, 0.f, 0.f};

  const int nt = K / BK;

  auto STAGE_A = [&](int h, int kt, int q) {
#pragma unroll
    for (int i = 0; i < 2; ++i) {
      int row = h * 128 + i * 64 + (tid >> 3);
      int L = q * BUFBYTES + row * 128 + ((tid & 7) << 4);
      int slot = (tid & 7) ^ (row & 7);
      gload_lds16(A + (size_t)(brow + row) * K + (size_t)kt * 64 + slot * 8,
                  lds + L);
    }
  };
  auto STAGE_B = [&](int h, int kt, int q) {
#pragma unroll
    for (int i = 0; i < 2; ++i) {
      int row = h * 128 + i * 64 + (tid >> 3);
      int L = q * BUFBYTES + OPBYTES + row * 128 + ((tid & 7) << 4);
      int slot = (tid & 7) ^ (row & 7);
      gload_lds16(B + (size_t)(bcol + row) * K + (size_t)kt * 64 + slot * 8,
                  lds + L);
    }
  };

  bf16x8 aq[8], blo[4], bhi[4];  // A quadrant [mm][kk]; B quadrants [nn][kk]
  auto READ_A = [&](int q, int mh) {
#pragma unroll
    for (int mm = 0; mm < 4; ++mm) {
      int off = q * BUFBYTES + aoffs[mh * 4 + mm];
      aq[mm * 2 + 0] = *reinterpret_cast<const bf16x8*>(lds + off);
      aq[mm * 2 + 1] = *reinterpret_cast<const bf16x8*>(lds + (off ^ 64));
    }
  };
  auto READ_B = [&](int q, int nh, bf16x8* dst) {
#pragma unroll
    for (int nn = 0; nn < 2; ++nn) {
      int off = q * BUFBYTES + OPBYTES + boffs[nh * 2 + nn];
      dst[nn * 2 + 0] = *reinterpret_cast<const bf16x8*>(lds + off);
      dst[nn * 2 + 1] = *reinterpret_cast<const bf16x8*>(lds + (off ^ 64));
    }
  };
  // kk-outer: no back-to-back dependent (same-acc) MFMAs.
  auto MMA = [&](int mh, int nh, const bf16x8* bb) {
    __builtin_amdgcn_s_setprio(1);
#pragma unroll
    for (int kk = 0; kk < 2; ++kk)
#pragma unroll
      for (int mm = 0; mm < 4; ++mm)
#pragma unroll
        for (int nn = 0; nn < 2; ++nn)
          acc[mh * 4 + mm][nh * 2 + nn] = __builtin_amdgcn_mfma_f32_16x16x32_bf16(
              aq[mm * 2 + kk], bb[nn * 2 + kk], acc[mh * 4 + mm][nh * 2 + nn],
              0, 0, 0);
    __builtin_amdgcn_s_setprio(0);
  };

  // Prologue: t0 full + t1 {B0,B1,A0} (14 loads); VM6 retires t0's 8,
  // keeps t1's 6 in flight (steady-state ph1 entry condition).
  STAGE_B(0, 0, 0); STAGE_B(1, 0, 0); STAGE_A(0, 0, 0); STAGE_A(1, 0, 0);
  STAGE_B(0, 1, 1); STAGE_B(1, 1, 1); STAGE_A(0, 1, 1);
  VM6();
  BARRIER();

  const int np = nt >> 1;
  for (int p = 0; p < np - 1; ++p) {
    const int t1 = 2 * p + 1, t2 = 2 * p + 2, t3 = 2 * p + 3;
    // ph1: buf0 (m-lo,n-lo); 12 reads; stage b1.A1(t1)
    READ_B(0, 0, blo); READ_A(0, 0);
    STAGE_A(1, t1, 1);
    LGKM8();
    BARRIER(); LGKM0();
    MMA(0, 0, blo);
    BARRIER();
    // ph2: (m-lo,n-hi); 4 reads; stage b0.B0(t2)
    READ_B(0, 1, bhi);
    STAGE_B(0, t2, 0);
    BARRIER(); LGKM0();
    MMA(0, 1, bhi);
    BARRIER();
    // ph3: (m-hi,n-hi); 8 reads; stage b0.B1(t2)
    READ_A(0, 1);
    STAGE_B(1, t2, 0);
    BARRIER(); LGKM0();
    MMA(1, 1, bhi);
    BARRIER();
    // ph4: (m-hi,n-lo); no reads; stage b0.A0(t2); VM6 retires tile t1
    STAGE_A(0, t2, 0);
    BARRIER();
    MMA(1, 0, blo);
    VM6();
    BARRIER();
    // ph5: buf1 (m-lo,n-lo); stage b0.A1(t2)
    READ_B(1, 0, blo); READ_A(1, 0);
    STAGE_A(1, t2, 0);
    LGKM8();
    BARRIER(); LGKM0();
    MMA(0, 0, blo);
    BARRIER();
    // ph6: stage b1.B0(t3)
    READ_B(1, 1, bhi);
    STAGE_B(0, t3, 1);
    BARRIER(); LGKM0();
    MMA(0, 1, bhi);
    BARRIER();
    // ph7: stage b1.B1(t3)
    READ_A(1, 1);
    STAGE_B(1, t3, 1);
    BARRIER(); LGKM0();
    MMA(1, 1, bhi);
    BARRIER();
    // ph8: stage b1.A0(t3); VM6 retires tile t2
    STAGE_A(0, t3, 1);
    BARRIER();
    MMA(1, 0, blo);
    VM6();
    BARRIER();
  }

  // Peeled final iteration (t0=nt-2, t1=nt-1): only ph1's stage; VM0 at ph4.
  {
    const int t1 = nt - 1;
    READ_B(0, 0, blo); READ_A(0, 0);
    STAGE_A(1, t1, 1);
    LGKM8();
    BARRIER(); LGKM0();
    MMA(0, 0, blo);
    BARRIER();
    READ_B(0, 1, bhi);
    BARRIER(); LGKM0();
    MMA(0, 1, bhi);
    BARRIER();
    READ_A(0, 1);
    BARRIER(); LGKM0();
    MMA(1, 1, bhi);
    BARRIER();
    BARRIER();
    MMA(1, 0, blo);
    VM0();
    BARRIER();
    READ_B(1, 0, blo); READ_A(1, 0);
    LGKM8();
    BARRIER(); LGKM0();
    MMA(0, 0, blo);
    BARRIER();
    READ_B(1, 1, bhi);
    BARRIER(); LGKM0();
    MMA(0, 1, bhi);
    BARRIER();
    READ_A(1, 1);
    BARRIER(); LGKM0();
    MMA(1, 1, bhi);
    BARRIER();
    MMA(1, 0, blo);
  }

  // Epilogue: C/D layout col=lane&15, row=(lane>>4)*4+reg  [m89/m91]
  // Agent-scope stores (replay-safe visibility past per-XCD L2).
  const int cn = lane & 15;
  const int r4 = (lane >> 4) << 2;
#pragma unroll
  for (int n = 0; n < 4; ++n) {
    const int gcol = bcol + wn * 64 + n * 16 + cn;
    const float bv = bias[gcol];
#pragma unroll
    for (int m = 0; m < 8; ++m) {
      const int grow = brow + wm * 128 + m * 16 + r4;
      float* outp = C + (size_t)grow * N + gcol;
#pragma unroll
      for (int j = 0; j < 4; ++j) {
        float v = acc[m][n][j] + bv;
        __hip_atomic_store(outp + (size_t)j * N, v, __ATOMIC_RELAXED,
                           __HIP_MEMORY_SCOPE_AGENT);
      }
    }
  }
}

extern "C" void kernel_launch(void* const* d_in, const int* in_sizes, int n_in,
                              void* d_out, int out_size, void* d_ws, size_t ws_size,
                              hipStream_t stream) {
  const float* x = (const float*)d_in[0];
  const float* W = (const float*)d_in[1];
  const float* b = (const float*)d_in[2];
  float* out = (float*)d_out;

  const int N = in_sizes[2];       // D_OUT
  const int K = in_sizes[1] / N;   // D_IN
  const int M = in_sizes[0] / K;   // B rows

  const size_t needA = (size_t)M * K * sizeof(bf16_t);
  const size_t needB = (size_t)N * K * sizeof(bf16_t);
  const bool tiled_ok = (M % BM == 0) && (N % BN == 0) && (K % (2 * BK) == 0) &&
                        (K / BK >= 2) && (ws_size >= needA + needB);
  if (!tiled_ok) {
    dim3 g((unsigned)((N + 255) / 256), (unsigned)M);
    naive_kernel<<<g, 256, 0, stream>>>(x, W, b, out, M, N, K);
    return;
  }

  bf16_t* qA = (bf16_t*)d_ws;
  bf16_t* qB = qA + (size_t)M * K;
  const long axn8 = (long)M * K / 8;
  const long totn8 = axn8 + (long)N * K / 8;
  quant2_bf16_kernel<<<2048, 256, 0, stream>>>(x, W, qA, axn8, totn8);

  (void)hipFuncSetAttribute((const void*)gemm_bt_bf16,
                            hipFuncAttributeMaxDynamicSharedMemorySize, LDS_TOTAL);

  const int nwg = (M / BM) * (N / BN);
  gemm_bt_bf16<<<nwg, THREADS, LDS_TOTAL, stream>>>(qA, qB, b, out, M, N, K);
}

// Round 15
// 162.317 us; speedup vs baseline: 1.1233x; 1.0252x over previous
//
#include <hip/hip_runtime.h>
#include <hip/hip_bf16.h>
#include <stdint.h>

typedef __hip_bfloat16 bf16_t;
typedef __attribute__((ext_vector_type(8))) __bf16 bf16x8;
typedef __attribute__((ext_vector_type(4))) float f32x4;
typedef __attribute__((ext_vector_type(8))) unsigned short ushort8;
typedef __attribute__((ext_vector_type(2))) unsigned long long u64x2;

#define BM 256
#define BN 256
#define BK 64
#define THREADS 512
#define OPBYTES 32768   // one operand per buf: 256 rows x 128 B
#define BUFBYTES 65536  // A + B
#define LDS_TOTAL 131072

// ---------------- fused quantize: q = rint(v*100)/100, cast to bf16 ----------------
// NT loads: x/W are read exactly once -> don't evict qA/qB (GEMM re-reads them
// ~16x via L2/LLC). Agent-scope stores for replay-safe cross-kernel visibility.
__global__ __launch_bounds__(256) void quant2_bf16_kernel(
    const float* __restrict__ x, const float* __restrict__ w,
    bf16_t* __restrict__ q, long axn8, long totn8) {
  long idx = (long)blockIdx.x * blockDim.x + threadIdx.x;
  long stride = (long)gridDim.x * blockDim.x;
  for (long i = idx; i < totn8; i += stride) {
    const float* src = (i < axn8) ? (x + i * 8) : (w + (i - axn8) * 8);
    const f32x4* p = reinterpret_cast<const f32x4*>(src);
    f32x4 v0 = __builtin_nontemporal_load(p);
    f32x4 v1 = __builtin_nontemporal_load(p + 1);
    float vv[8] = {v0[0], v0[1], v0[2], v0[3], v1[0], v1[1], v1[2], v1[3]};
    ushort8 r;
#pragma unroll
    for (int j = 0; j < 8; ++j) {
      float qq = rintf(vv[j] * 100.0f) / 100.0f;  // half-to-even, matches jnp.round
      __hip_bfloat16 h = __float2bfloat16(qq);
      r[j] = __builtin_bit_cast(unsigned short, h);
    }
    u64x2 u = __builtin_bit_cast(u64x2, r);
    unsigned long long* dst = reinterpret_cast<unsigned long long*>(q + i * 8);
    __hip_atomic_store(dst + 0, u[0], __ATOMIC_RELAXED, __HIP_MEMORY_SCOPE_AGENT);
    __hip_atomic_store(dst + 1, u[1], __ATOMIC_RELAXED, __HIP_MEMORY_SCOPE_AGENT);
  }
}

// ---------------- fallback ----------------
__global__ void naive_kernel(const float* __restrict__ x, const float* __restrict__ W,
                             const float* __restrict__ b, float* __restrict__ out,
                             int M, int N, int K) {
  int o = blockIdx.x * blockDim.x + threadIdx.x;
  int m = blockIdx.y;
  if (o >= N || m >= M) return;
  float s = 0.f;
  for (int k = 0; k < K; ++k) {
    float qx = rintf(x[(size_t)m * K + k] * 100.f) / 100.f;
    float qw = rintf(W[(size_t)o * K + k] * 100.f) / 100.f;
    s += qx * qw;
  }
  float v = s + b[o];
  __hip_atomic_store(out + (size_t)m * N + o, v, __ATOMIC_RELAXED,
                     __HIP_MEMORY_SCOPE_AGENT);
}

__device__ __forceinline__ void gload_lds16(const bf16_t* g, const char* l) {
  __builtin_amdgcn_global_load_lds(
      (const __attribute__((address_space(1))) unsigned int*)g,
      (__attribute__((address_space(3))) unsigned int*)l, 16, 0, 0);
}

#define BARRIER()                               \
  do {                                          \
    asm volatile("" ::: "memory");              \
    __builtin_amdgcn_s_barrier();               \
    asm volatile("" ::: "memory");              \
  } while (0)
#define VM8() asm volatile("s_waitcnt vmcnt(8)" ::: "memory")
#define VM0() asm volatile("s_waitcnt vmcnt(0)" ::: "memory")

// ---------------- bf16 GEMM, B^T input: C[m][n] = sum_k A[m][k]*B[n][k] + bias[n]
// BEST MEASURED CONFIG (round 11; 121.5-123.0 us GEMM, MfmaUtil 48.6, 0 bank
// conflicts): 8 phases, ONE barrier per phase, deep-prefetch bunched stages,
// tail pre-reads, compiler-managed lgkmcnt.
// Campaign record at this geometry (256^2 tile, 8 waves, BK=64, 2 LDS bufs):
//   r9 wider phases -41%; r10 2-blocks/CU -15%; r13 32x32 MFMA -18% (4-way
//   LDS conflicts inherent to 128B rows); r14 two-barrier m201 discipline -7%;
//   r8/r11/r12 intra-variants all within noise. Sharp local optimum.
//
// Read schedule (buf0 half; buf1 mirrors):
//   ph1-top:  blo + A-lo (12)  [buf-switch burst: pre-reading across the
//             ph8/ph4 barrier would race other waves' un-vmcnt'd DMA]
//   ph1-tail: bhi (4) -> consumed ph2
//   ph2-tail: A-hi (8) -> consumed ph3/ph4 (WAR on aq after MMA(0,1))
//   ph3, ph4: no reads.
// Stage/vmcnt ledger (r8-proven): stages ph3(b0.B t2, 4 loads), ph4(b0.A t2),
//   ph7(b1.B t3), ph8(b1.A t3); VM8 at ph4 retires carried b1(t1) [4-6 phases
//   old], at ph8 retires b0(t2). Prologue: both tiles fully staged (16 loads),
//   VM8 retires b0's 8. WAR: each region staged >=1 barrier after its last
//   read (B read ph2 -> staged ph3; A read ph3 -> ph4; mirrors ph6->ph7,
//   ph7->ph8). LAST iteration PEELED: no stages; VM0 at ph4.
// LDS swizzle: 128B rows, stored slot = slot ^ (row&7) (0 conflicts measured
// r2-r12). global_load_lds dest linear (base+lane*16); swizzle applied on the
// global SOURCE address (rule #21).
__global__ __launch_bounds__(THREADS, 2) void gemm_bt_bf16(
    const bf16_t* __restrict__ A,   // [M][K]
    const bf16_t* __restrict__ B,   // [N][K]
    const float* __restrict__ bias, // [N]
    float* __restrict__ C,          // [M][N]
    int M, int N, int K) {
  extern __shared__ char lds[];

  const int tid = threadIdx.x;
  const int lane = tid & 63;
  const int wave = tid >> 6;  // 0..7
  const int wm = wave >> 2;   // 0..1 -> output rows wm*128..+128
  const int wn = wave & 3;    // 0..3 -> output cols wn*64..+64
  const int lr = lane & 15;
  const int lg = lane >> 4;

  // XCD-aware bijective swizzle (nwg % 8 == 0 guaranteed by tiled_ok)
  int nbn = N / BN;
  int nwg = gridDim.x;
  int bid = blockIdx.x;
  int swz = bid;
  if ((nwg & 7) == 0) {
    int cpx = nwg >> 3;
    swz = (bid & 7) * cpx + (bid >> 3);
  }
  const int brow = (swz / nbn) * BM;
  const int bcol = (swz % nbn) * BN;

  // ds_read byte offsets within an operand region (kk=0; kk=1 is ^64)
  int aoffs[8], boffs[4];
#pragma unroll
  for (int m = 0; m < 8; ++m) {
    int r = wm * 128 + m * 16 + lr;
    aoffs[m] = r * 128 + (((lg) ^ (r & 7)) << 4);
  }
#pragma unroll
  for (int n = 0; n < 4; ++n) {
    int r = wn * 64 + n * 16 + lr;
    boffs[n] = r * 128 + (((lg) ^ (r & 7)) << 4);
  }

  f32x4 acc[8][4];
#pragma unroll
  for (int m = 0; m < 8; ++m)
#pragma unroll
    for (int n = 0; n < 4; ++n) acc[m][n] = (f32x4){0.f, 0.f, 0.f, 0.f};

  const int nt = K / BK;

  auto STAGE_A = [&](int h, int kt, int q) {
#pragma unroll
    for (int i = 0; i < 2; ++i) {
      int row = h * 128 + i * 64 + (tid >> 3);
      int L = q * BUFBYTES + row * 128 + ((tid & 7) << 4);
      int slot = (tid & 7) ^ (row & 7);
      gload_lds16(A + (size_t)(brow + row) * K + (size_t)kt * 64 + slot * 8,
                  lds + L);
    }
  };
  auto STAGE_B = [&](int h, int kt, int q) {
#pragma unroll
    for (int i = 0; i < 2; ++i) {
      int row = h * 128 + i * 64 + (tid >> 3);
      int L = q * BUFBYTES + OPBYTES + row * 128 + ((tid & 7) << 4);
      int slot = (tid & 7) ^ (row & 7);
      gload_lds16(B + (size_t)(bcol + row) * K + (size_t)kt * 64 + slot * 8,
                  lds + L);
    }
  };

  bf16x8 aq[8], blo[4], bhi[4];  // A quadrant [mm][kk]; B quadrants [nn][kk]
  auto READ_A = [&](int q, int mh) {
#pragma unroll
    for (int mm = 0; mm < 4; ++mm) {
      int off = q * BUFBYTES + aoffs[mh * 4 + mm];
      aq[mm * 2 + 0] = *reinterpret_cast<const bf16x8*>(lds + off);
      aq[mm * 2 + 1] = *reinterpret_cast<const bf16x8*>(lds + (off ^ 64));
    }
  };
  auto READ_B = [&](int q, int nh, bf16x8* dst) {
#pragma unroll
    for (int nn = 0; nn < 2; ++nn) {
      int off = q * BUFBYTES + OPBYTES + boffs[nh * 2 + nn];
      dst[nn * 2 + 0] = *reinterpret_cast<const bf16x8*>(lds + off);
      dst[nn * 2 + 1] = *reinterpret_cast<const bf16x8*>(lds + (off ^ 64));
    }
  };
  auto MMA = [&](int mh, int nh, const bf16x8* bb) {
    __builtin_amdgcn_s_setprio(1);
#pragma unroll
    for (int mm = 0; mm < 4; ++mm)
#pragma unroll
      for (int nn = 0; nn < 2; ++nn)
#pragma unroll
        for (int kk = 0; kk < 2; ++kk)
          acc[mh * 4 + mm][nh * 2 + nn] = __builtin_amdgcn_mfma_f32_16x16x32_bf16(
              aq[mm * 2 + kk], bb[nn * 2 + kk], acc[mh * 4 + mm][nh * 2 + nn],
              0, 0, 0);
    __builtin_amdgcn_s_setprio(0);
  };

  // Prologue: both tiles fully staged; b0's 8 retired, b1's 8 carried in flight.
  STAGE_B(0, 0, 0); STAGE_B(1, 0, 0); STAGE_A(0, 0, 0); STAGE_A(1, 0, 0);
  STAGE_B(0, 1, 1); STAGE_B(1, 1, 1); STAGE_A(0, 1, 1); STAGE_A(1, 1, 1);
  VM8();
  BARRIER();

  const int np = nt >> 1;
  for (int p = 0; p < np - 1; ++p) {
    const int t2 = 2 * p + 2, t3 = 2 * p + 3;
    // ph1: buf0 (m-lo,n-lo). Top-burst (unavoidable at buf switch), then
    // tail pre-read of bhi for ph2.
    READ_B(0, 0, blo); READ_A(0, 0);
    MMA(0, 0, blo);
    READ_B(0, 1, bhi);
    BARRIER();
    // ph2: (m-lo,n-hi) — operands pre-read. Tail pre-read A-hi for ph3/ph4.
    MMA(0, 1, bhi);
    READ_A(0, 1);
    BARRIER();
    // ph3: (m-hi,n-hi) — no reads; stage b0.B(t2) (B reads delivered by ph2)
    STAGE_B(0, t2, 0); STAGE_B(1, t2, 0);
    MMA(1, 1, bhi);
    BARRIER();
    // ph4: (m-hi,n-lo) — no reads; stage b0.A(t2); retire carried b1(t1)
    STAGE_A(0, t2, 0); STAGE_A(1, t2, 0);
    MMA(1, 0, blo);
    VM8();
    BARRIER();
    // ph5: buf1 — mirror of ph1
    READ_B(1, 0, blo); READ_A(1, 0);
    MMA(0, 0, blo);
    READ_B(1, 1, bhi);
    BARRIER();
    // ph6 — mirror of ph2
    MMA(0, 1, bhi);
    READ_A(1, 1);
    BARRIER();
    // ph7 — stage b1.B(t3)
    STAGE_B(0, t3, 1); STAGE_B(1, t3, 1);
    MMA(1, 1, bhi);
    BARRIER();
    // ph8 — stage b1.A(t3); retire b0(t2)
    STAGE_A(0, t3, 1); STAGE_A(1, t3, 1);
    MMA(1, 0, blo);
    VM8();
    BARRIER();
  }

  // Peeled final iteration (r8-proven): read-at-top, no stages, VM0 at ph4.
  {
    READ_B(0, 0, blo); READ_A(0, 0);
    MMA(0, 0, blo);
    BARRIER();
    READ_B(0, 1, bhi);
    MMA(0, 1, bhi);
    BARRIER();
    READ_A(0, 1);
    MMA(1, 1, bhi);
    BARRIER();
    MMA(1, 0, blo);
    VM0();
    BARRIER();
    READ_B(1, 0, blo); READ_A(1, 0);
    MMA(0, 0, blo);
    BARRIER();
    READ_B(1, 1, bhi);
    MMA(0, 1, bhi);
    BARRIER();
    READ_A(1, 1);
    MMA(1, 1, bhi);
    BARRIER();
    MMA(1, 0, blo);
  }

  // Epilogue: C/D layout col=lane&15, row=(lane>>4)*4+reg  [m89/m91]
  // Agent-scope stores (replay-safe visibility past per-XCD L2).
  const int cn = lane & 15;
  const int r4 = (lane >> 4) << 2;
#pragma unroll
  for (int n = 0; n < 4; ++n) {
    const int gcol = bcol + wn * 64 + n * 16 + cn;
    const float bv = bias[gcol];
#pragma unroll
    for (int m = 0; m < 8; ++m) {
      const int grow = brow + wm * 128 + m * 16 + r4;
      float* outp = C + (size_t)grow * N + gcol;
#pragma unroll
      for (int j = 0; j < 4; ++j) {
        float v = acc[m][n][j] + bv;
        __hip_atomic_store(outp + (size_t)j * N, v, __ATOMIC_RELAXED,
                           __HIP_MEMORY_SCOPE_AGENT);
      }
    }
  }
}

extern "C" void kernel_launch(void* const* d_in, const int* in_sizes, int n_in,
                              void* d_out, int out_size, void* d_ws, size_t ws_size,
                              hipStream_t stream) {
  const float* x = (const float*)d_in[0];
  const float* W = (const float*)d_in[1];
  const float* b = (const float*)d_in[2];
  float* out = (float*)d_out;

  const int N = in_sizes[2];       // D_OUT
  const int K = in_sizes[1] / N;   // D_IN
  const int M = in_sizes[0] / K;   // B rows

  const size_t needA = (size_t)M * K * sizeof(bf16_t);
  const size_t needB = (size_t)N * K * sizeof(bf16_t);
  const bool tiled_ok = (M % BM == 0) && (N % BN == 0) && (K % (2 * BK) == 0) &&
                        (K / BK >= 2) && (ws_size >= needA + needB);
  if (!tiled_ok) {
    dim3 g((unsigned)((N + 255) / 256), (unsigned)M);
    naive_kernel<<<g, 256, 0, stream>>>(x, W, b, out, M, N, K);
    return;
  }

  bf16_t* qA = (bf16_t*)d_ws;
  bf16_t* qB = qA + (size_t)M * K;
  const long axn8 = (long)M * K / 8;
  const long totn8 = axn8 + (long)N * K / 8;
  quant2_bf16_kernel<<<2048, 256, 0, stream>>>(x, W, qA, axn8, totn8);

  (void)hipFuncSetAttribute((const void*)gemm_bt_bf16,
                            hipFuncAttributeMaxDynamicSharedMemorySize, LDS_TOTAL);

  const int nwg = (M / BM) * (N / BN);
  gemm_bt_bf16<<<nwg, THREADS, LDS_TOTAL, stream>>>(qA, qB, b, out, M, N, K);
}

// Round 16
// 162.102 us; speedup vs baseline: 1.1248x; 1.0013x over previous
//
#include <hip/hip_runtime.h>
#include <hip/hip_bf16.h>
#include <stdint.h>

typedef __hip_bfloat16 bf16_t;
typedef __attribute__((ext_vector_type(8))) __bf16 bf16x8;
typedef __attribute__((ext_vector_type(4))) float f32x4;
typedef __attribute__((ext_vector_type(8))) unsigned short ushort8;
typedef __attribute__((ext_vector_type(2))) unsigned long long u64x2;

#define BM 256
#define BN 256
#define BK 64
#define THREADS 512
#define OPBYTES 32768   // one operand per buf: 256 rows x 128 B
#define BUFBYTES 65536  // A + B
#define LDS_TOTAL 131072

// ---------------- fused quantize: q = rint(v*100)/100, cast to bf16 ----------------
// NT loads: x/W are read exactly once -> don't evict qA/qB (GEMM re-reads them
// ~16x via L2/LLC). Agent-scope stores for replay-safe cross-kernel visibility.
__global__ __launch_bounds__(256) void quant2_bf16_kernel(
    const float* __restrict__ x, const float* __restrict__ w,
    bf16_t* __restrict__ q, long axn8, long totn8) {
  long idx = (long)blockIdx.x * blockDim.x + threadIdx.x;
  long stride = (long)gridDim.x * blockDim.x;
  for (long i = idx; i < totn8; i += stride) {
    const float* src = (i < axn8) ? (x + i * 8) : (w + (i - axn8) * 8);
    const f32x4* p = reinterpret_cast<const f32x4*>(src);
    f32x4 v0 = __builtin_nontemporal_load(p);
    f32x4 v1 = __builtin_nontemporal_load(p + 1);
    float vv[8] = {v0[0], v0[1], v0[2], v0[3], v1[0], v1[1], v1[2], v1[3]};
    ushort8 r;
#pragma unroll
    for (int j = 0; j < 8; ++j) {
      float qq = rintf(vv[j] * 100.0f) / 100.0f;  // half-to-even, matches jnp.round
      __hip_bfloat16 h = __float2bfloat16(qq);
      r[j] = __builtin_bit_cast(unsigned short, h);
    }
    u64x2 u = __builtin_bit_cast(u64x2, r);
    unsigned long long* dst = reinterpret_cast<unsigned long long*>(q + i * 8);
    __hip_atomic_store(dst + 0, u[0], __ATOMIC_RELAXED, __HIP_MEMORY_SCOPE_AGENT);
    __hip_atomic_store(dst + 1, u[1], __ATOMIC_RELAXED, __HIP_MEMORY_SCOPE_AGENT);
  }
}

// ---------------- fallback ----------------
__global__ void naive_kernel(const float* __restrict__ x, const float* __restrict__ W,
                             const float* __restrict__ b, float* __restrict__ out,
                             int M, int N, int K) {
  int o = blockIdx.x * blockDim.x + threadIdx.x;
  int m = blockIdx.y;
  if (o >= N || m >= M) return;
  float s = 0.f;
  for (int k = 0; k < K; ++k) {
    float qx = rintf(x[(size_t)m * K + k] * 100.f) / 100.f;
    float qw = rintf(W[(size_t)o * K + k] * 100.f) / 100.f;
    s += qx * qw;
  }
  float v = s + b[o];
  __hip_atomic_store(out + (size_t)m * N + o, v, __ATOMIC_RELAXED,
                     __HIP_MEMORY_SCOPE_AGENT);
}

__device__ __forceinline__ void gload_lds16(const bf16_t* g, const char* l) {
  __builtin_amdgcn_global_load_lds(
      (const __attribute__((address_space(1))) unsigned int*)g,
      (__attribute__((address_space(3))) unsigned int*)l, 16, 0, 0);
}

#define BARRIER()                               \
  do {                                          \
    asm volatile("" ::: "memory");              \
    __builtin_amdgcn_s_barrier();               \
    asm volatile("" ::: "memory");              \
  } while (0)
#define VM8() asm volatile("s_waitcnt vmcnt(8)" ::: "memory")
#define VM0() asm volatile("s_waitcnt vmcnt(0)" ::: "memory")

// ---------------- bf16 GEMM, B^T input: C[m][n] = sum_k A[m][k]*B[n][k] + bias[n]
// ROUND 16 = r11/r15 (best measured: 120.5 us GEMM, MfmaUtil 49.8, 0 conflicts)
// with the 4 PROVABLY-REDUNDANT barriers removed (8 -> 4 per iter).
// Hazard audit of r11: ALL of buf0's LDS reads complete by ph2 (blo/Alo at
// ph1-top, bhi at ph1-tail, Ahi at ph2-tail); buf0's stages are at ph3/ph4.
// Required orderings are ONLY:
//   (1) end-of-A0 barrier: all buf0 reads  <  buf0 stages (WAR)
//   (2) end-of-B0 barrier after VM8: b1(t1) landed  <  buf1 reads (RAW)
//   and mirrors (3),(4) for buf1. The barriers at end-ph1/ph3/ph5/ph7 protect
//   no LDS hazard -> removed. Two superphases per buffer:
//     A = { 12 reads; MMA(0,0); 4 reads; MMA(0,1); 8 reads }  BARRIER
//     B = { stage B; MMA(1,1); stage A; MMA(1,0); VM8 }        BARRIER
// Mechanisms: (a) r14 measured ~80cy per barrier resync -> -4/iter;
// (b) within a superphase waves skew freely, so one wave's ds_read burst
// overlaps another's MFMA drain (LDS pipe 2312cy vs matrix 1242cy per A) --
// the cross-wave overlap that full lockstep forbade. Unlike r9 (-41%), the
// prefetch ledger is UNTOUCHED (r11's proven VM8, 4-6-phase-old loads):
//   entering iter: 8 in flight (b1<-t1, staged prev B1). B0 stages b0<-t2
//   (+8=16); VM8 retires exactly b1(t1) (needed by A1, after this barrier).
//   B1 stages b1<-t3; VM8 retires exactly b0(t2) (needed next A0).
//   Prologue: 16 loads, VM8 retires b0(t0). PEELED last iter: no stages,
//   VM0 in B0 (drains b1(nt-1) before A1 reads it).
// LDS swizzle: 128B rows, stored slot = slot ^ (row&7) (0 conflicts measured
// r2-r15). global_load_lds dest linear (base+lane*16); swizzle applied on the
// global SOURCE address (rule #21).
__global__ __launch_bounds__(THREADS, 2) void gemm_bt_bf16(
    const bf16_t* __restrict__ A,   // [M][K]
    const bf16_t* __restrict__ B,   // [N][K]
    const float* __restrict__ bias, // [N]
    float* __restrict__ C,          // [M][N]
    int M, int N, int K) {
  extern __shared__ char lds[];

  const int tid = threadIdx.x;
  const int lane = tid & 63;
  const int wave = tid >> 6;  // 0..7
  const int wm = wave >> 2;   // 0..1 -> output rows wm*128..+128
  const int wn = wave & 3;    // 0..3 -> output cols wn*64..+64
  const int lr = lane & 15;
  const int lg = lane >> 4;

  // XCD-aware bijective swizzle (nwg % 8 == 0 guaranteed by tiled_ok)
  int nbn = N / BN;
  int nwg = gridDim.x;
  int bid = blockIdx.x;
  int swz = bid;
  if ((nwg & 7) == 0) {
    int cpx = nwg >> 3;
    swz = (bid & 7) * cpx + (bid >> 3);
  }
  const int brow = (swz / nbn) * BM;
  const int bcol = (swz % nbn) * BN;

  // ds_read byte offsets within an operand region (kk=0; kk=1 is ^64)
  int aoffs[8], boffs[4];
#pragma unroll
  for (int m = 0; m < 8; ++m) {
    int r = wm * 128 + m * 16 + lr;
    aoffs[m] = r * 128 + (((lg) ^ (r & 7)) << 4);
  }
#pragma unroll
  for (int n = 0; n < 4; ++n) {
    int r = wn * 64 + n * 16 + lr;
    boffs[n] = r * 128 + (((lg) ^ (r & 7)) << 4);
  }

  f32x4 acc[8][4];
#pragma unroll
  for (int m = 0; m < 8; ++m)
#pragma unroll
    for (int n = 0; n < 4; ++n) acc[m][n] = (f32x4){0.f, 0.f, 0.f, 0.f};

  const int nt = K / BK;

  auto STAGE_A = [&](int h, int kt, int q) {
#pragma unroll
    for (int i = 0; i < 2; ++i) {
      int row = h * 128 + i * 64 + (tid >> 3);
      int L = q * BUFBYTES + row * 128 + ((tid & 7) << 4);
      int slot = (tid & 7) ^ (row & 7);
      gload_lds16(A + (size_t)(brow + row) * K + (size_t)kt * 64 + slot * 8,
                  lds + L);
    }
  };
  auto STAGE_B = [&](int h, int kt, int q) {
#pragma unroll
    for (int i = 0; i < 2; ++i) {
      int row = h * 128 + i * 64 + (tid >> 3);
      int L = q * BUFBYTES + OPBYTES + row * 128 + ((tid & 7) << 4);
      int slot = (tid & 7) ^ (row & 7);
      gload_lds16(B + (size_t)(bcol + row) * K + (size_t)kt * 64 + slot * 8,
                  lds + L);
    }
  };

  bf16x8 aq[8], blo[4], bhi[4];  // A quadrant [mm][kk]; B quadrants [nn][kk]
  auto READ_A = [&](int q, int mh) {
#pragma unroll
    for (int mm = 0; mm < 4; ++mm) {
      int off = q * BUFBYTES + aoffs[mh * 4 + mm];
      aq[mm * 2 + 0] = *reinterpret_cast<const bf16x8*>(lds + off);
      aq[mm * 2 + 1] = *reinterpret_cast<const bf16x8*>(lds + (off ^ 64));
    }
  };
  auto READ_B = [&](int q, int nh, bf16x8* dst) {
#pragma unroll
    for (int nn = 0; nn < 2; ++nn) {
      int off = q * BUFBYTES + OPBYTES + boffs[nh * 2 + nn];
      dst[nn * 2 + 0] = *reinterpret_cast<const bf16x8*>(lds + off);
      dst[nn * 2 + 1] = *reinterpret_cast<const bf16x8*>(lds + (off ^ 64));
    }
  };
  auto MMA = [&](int mh, int nh, const bf16x8* bb) {
    __builtin_amdgcn_s_setprio(1);
#pragma unroll
    for (int mm = 0; mm < 4; ++mm)
#pragma unroll
      for (int nn = 0; nn < 2; ++nn)
#pragma unroll
        for (int kk = 0; kk < 2; ++kk)
          acc[mh * 4 + mm][nh * 2 + nn] = __builtin_amdgcn_mfma_f32_16x16x32_bf16(
              aq[mm * 2 + kk], bb[nn * 2 + kk], acc[mh * 4 + mm][nh * 2 + nn],
              0, 0, 0);
    __builtin_amdgcn_s_setprio(0);
  };

  // Prologue: both tiles fully staged; b0's 8 retired, b1's 8 carried in flight.
  STAGE_B(0, 0, 0); STAGE_B(1, 0, 0); STAGE_A(0, 0, 0); STAGE_A(1, 0, 0);
  STAGE_B(0, 1, 1); STAGE_B(1, 1, 1); STAGE_A(0, 1, 1); STAGE_A(1, 1, 1);
  VM8();
  BARRIER();

  const int np = nt >> 1;
  for (int p = 0; p < np - 1; ++p) {
    const int t2 = 2 * p + 2, t3 = 2 * p + 3;
    // superphase A0: ALL buf0 reads interleaved with the m-lo MFMAs.
    READ_B(0, 0, blo); READ_A(0, 0);
    MMA(0, 0, blo);
    READ_B(0, 1, bhi);
    MMA(0, 1, bhi);
    READ_A(0, 1);
    BARRIER();  // (1) all buf0 reads < buf0 stages
    // superphase B0: stages b0<-t2 + m-hi MFMAs; VM8 retires b1(t1).
    STAGE_B(0, t2, 0); STAGE_B(1, t2, 0);
    MMA(1, 1, bhi);
    STAGE_A(0, t2, 0); STAGE_A(1, t2, 0);
    MMA(1, 0, blo);
    VM8();
    BARRIER();  // (2) b1(t1) landed < buf1 reads
    // superphase A1: mirror on buf1.
    READ_B(1, 0, blo); READ_A(1, 0);
    MMA(0, 0, blo);
    READ_B(1, 1, bhi);
    MMA(0, 1, bhi);
    READ_A(1, 1);
    BARRIER();  // (3)
    // superphase B1: stages b1<-t3; VM8 retires b0(t2).
    STAGE_B(0, t3, 1); STAGE_B(1, t3, 1);
    MMA(1, 1, bhi);
    STAGE_A(0, t3, 1); STAGE_A(1, t3, 1);
    MMA(1, 0, blo);
    VM8();
    BARRIER();  // (4)
  }

  // Peeled final iteration: no stages; VM0 in B0 (drains carried b1 loads).
  {
    READ_B(0, 0, blo); READ_A(0, 0);
    MMA(0, 0, blo);
    READ_B(0, 1, bhi);
    MMA(0, 1, bhi);
    READ_A(0, 1);
    BARRIER();
    MMA(1, 1, bhi);
    MMA(1, 0, blo);
    VM0();
    BARRIER();
    READ_B(1, 0, blo); READ_A(1, 0);
    MMA(0, 0, blo);
    READ_B(1, 1, bhi);
    MMA(0, 1, bhi);
    READ_A(1, 1);
    BARRIER();
    MMA(1, 1, bhi);
    MMA(1, 0, blo);
  }

  // Epilogue: C/D layout col=lane&15, row=(lane>>4)*4+reg  [m89/m91]
  // Agent-scope stores (replay-safe visibility past per-XCD L2).
  const int cn = lane & 15;
  const int r4 = (lane >> 4) << 2;
#pragma unroll
  for (int n = 0; n < 4; ++n) {
    const int gcol = bcol + wn * 64 + n * 16 + cn;
    const float bv = bias[gcol];
#pragma unroll
    for (int m = 0; m < 8; ++m) {
      const int grow = brow + wm * 128 + m * 16 + r4;
      float* outp = C + (size_t)grow * N + gcol;
#pragma unroll
      for (int j = 0; j < 4; ++j) {
        float v = acc[m][n][j] + bv;
        __hip_atomic_store(outp + (size_t)j * N, v, __ATOMIC_RELAXED,
                           __HIP_MEMORY_SCOPE_AGENT);
      }
    }
  }
}

extern "C" void kernel_launch(void* const* d_in, const int* in_sizes, int n_in,
                              void* d_out, int out_size, void* d_ws, size_t ws_size,
                              hipStream_t stream) {
  const float* x = (const float*)d_in[0];
  const float* W = (const float*)d_in[1];
  const float* b = (const float*)d_in[2];
  float* out = (float*)d_out;

  const int N = in_sizes[2];       // D_OUT
  const int K = in_sizes[1] / N;   // D_IN
  const int M = in_sizes[0] / K;   // B rows

  const size_t needA = (size_t)M * K * sizeof(bf16_t);
  const size_t needB = (size_t)N * K * sizeof(bf16_t);
  const bool tiled_ok = (M % BM == 0) && (N % BN == 0) && (K % (2 * BK) == 0) &&
                        (K / BK >= 2) && (ws_size >= needA + needB);
  if (!tiled_ok) {
    dim3 g((unsigned)((N + 255) / 256), (unsigned)M);
    naive_kernel<<<g, 256, 0, stream>>>(x, W, b, out, M, N, K);
    return;
  }

  bf16_t* qA = (bf16_t*)d_ws;
  bf16_t* qB = qA + (size_t)M * K;
  const long axn8 = (long)M * K / 8;
  const long totn8 = axn8 + (long)N * K / 8;
  quant2_bf16_kernel<<<2048, 256, 0, stream>>>(x, W, qA, axn8, totn8);

  (void)hipFuncSetAttribute((const void*)gemm_bt_bf16,
                            hipFuncAttributeMaxDynamicSharedMemorySize, LDS_TOTAL);

  const int nwg = (M / BM) * (N / BN);
  gemm_bt_bf16<<<nwg, THREADS, LDS_TOTAL, stream>>>(qA, qB, b, out, M, N, K);
}